// Round 7
// baseline (485.698 us; speedup 1.0000x reference)
//
#include <hip/hip_runtime.h>
#include <stdint.h>

// ---------------------------------------------------------------------------
// scores[b,s] = v . tanh( hidden[b] @ Wh + bias + enc[s,b] @ We )
// out[b,s]   = softmax_s(scores)
// Big GEMM: enc_flat[M=65536,K=1024] @ We[K=1024,N=512], bf16 MFMA.
// R8: barrier-free GEMM. Rounds 3-7 showed the wall is exposed latency
//     re-paid at every barrier-locked phase (convoy over ~200 outstanding
//     loads/CU), not BW/conflicts/occupancy. The barrier existed only for
//     the in-LDS A transpose -> moved off critical path: new aconv pass
//     stores enc as bf16 PRE-PACKED in MFMA A-fragment lane order (the R5
//     trick that fixed B). GEMM now loads A and B fragments straight from
//     global, coalesced, no LDS, no barriers; waves free-run/self-stagger.
//     Workspace: poison fill = 1.074 GB -> ws ~1 GiB; Apack 128 MB fits.
// ---------------------------------------------------------------------------

typedef float  floatx4 __attribute__((ext_vector_type(4)));
typedef __bf16 bf16x4  __attribute__((ext_vector_type(4)));
typedef __bf16 bf16x8  __attribute__((ext_vector_type(8)));
typedef short  short8  __attribute__((ext_vector_type(8)));

union bfu { bf16x8 v; short8 s; };

#define LOG2E_X2 2.8853900817779268f
#define SB() __builtin_amdgcn_sched_barrier(0)

// ---- kernel 0: W[512:1536,:] -> fragment-packed bf16 B.
// Bp frag(T,wc,ct) base elem = ((T*4+wc)*8+ct)*512; lane (q*16+t) holds 8 k.
__global__ void wt_convert(const float* __restrict__ W, __bf16* __restrict__ Bp) {
  __shared__ float tile[64][65];                 // +1 pad: conflict-free both ways
  const int kt = blockIdx.x >> 3;                // 16 k-tiles (64 k each)
  const int nt = blockIdx.x & 7;                 // 8 n-tiles (64 n each)
  const int c  = threadIdx.x & 63;
  const int r4 = threadIdx.x >> 6;               // 4 rows per pass
  #pragma unroll 4
  for (int i = 0; i < 16; i++) {
    int r = i * 4 + r4;                          // k-local
    tile[r][c] = W[(long)(512 + kt * 64 + r) * 512 + nt * 64 + c];
  }
  __syncthreads();
  // pack: 8 consecutive k -> one 16B chunk per thread
  const int n_loc = threadIdx.x & 63;
  const int kc4   = threadIdx.x >> 6;            // 0..3
  const int n_g   = nt * 64 + n_loc;
  const int wc    = n_g >> 7;
  const int ct    = (n_g >> 4) & 7;
  const int t     = n_g & 15;
  #pragma unroll
  for (int i = 0; i < 2; i++) {
    int chunk = i * 4 + kc4;                     // k_loc = chunk*8 + j
    int k_g   = kt * 64 + chunk * 8;
    int T     = k_g >> 5;
    int q     = (k_g >> 3) & 3;
    union bfu u;
    #pragma unroll
    for (int j = 0; j < 8; j++) u.v[j] = (__bf16)tile[chunk * 8 + j][n_loc];
    long cidx = ((long)(T * 4 + wc) * 8 + ct) * 64 + q * 16 + t;
    *(bf16x8*)(Bp + cidx * 8) = u.v;
  }
}

// ---- kernel 1: hproj[b][n] = bias[n] + sum_k hidden[b,k] * W[k,n]  (k<512)
__global__ void hproj_kernel(const float* __restrict__ hidden,
                             const float* __restrict__ W,
                             const float* __restrict__ bias,
                             float* __restrict__ hproj) {
  const int tid = threadIdx.x;            // n
  const int b_  = blockIdx.x >> 2;
  const int kc  = blockIdx.x & 3;
  __shared__ float hid[128];
  if (tid < 128) hid[tid] = hidden[b_ * 512 + kc * 128 + tid];
  __syncthreads();
  float acc = (kc == 0) ? bias[tid] : 0.f;
  const float* Wp = W + (long)(kc * 128) * 512 + tid;
  #pragma unroll 8
  for (int k = 0; k < 128; k++) acc = fmaf(hid[k], Wp[(long)k * 512], acc);
  atomicAdd(&hproj[b_ * 512 + tid], acc);
}

// ---- kernel 1.5: enc fp32 -> fragment-packed bf16 A.
// Apack chunk ((R*32+T)*4 + rt): lane l=q*16+t holds
//   bf16(enc[R*64 + rt*16 + t][T*32 + q*8 + j]), j=0..7  (16B/lane).
// One block per 64-row R-tile; 4 stripes of 16 rows through a 33KB LDS.
__global__ void aconv_kernel(const float* __restrict__ enc,
                             __bf16* __restrict__ Apack) {
  __shared__ __bf16 lds16[16][1026];             // stride 1026: 2-way max read
  const int R  = blockIdx.x;
  const int u  = threadIdx.x;
  const int rl = u >> 4;                         // row in stripe, 0..15
  const int cb = u & 15;                         // col-block
  const int l  = u & 63;
  const int w4 = u >> 6;                         // 0..3
  const int q  = l >> 4, t = l & 15;
  for (int s3 = 0; s3 < 4; s3++) {               // s3 == rt
    const float* src = enc + ((long)(R * 64 + s3 * 16 + rl)) * 1024 + cb * 4;
    #pragma unroll
    for (int i = 0; i < 16; i++) {
      floatx4 v4 = *(const floatx4*)(src + i * 64);
      bf16x4 b4;
      b4[0] = (__bf16)v4[0]; b4[1] = (__bf16)v4[1];
      b4[2] = (__bf16)v4[2]; b4[3] = (__bf16)v4[3];
      *(bf16x4*)(&lds16[rl][cb * 4 + i * 64]) = b4;
    }
    __syncthreads();
    #pragma unroll
    for (int i = 0; i < 8; i++) {
      int T = i * 4 + w4;
      bf16x8 val = *(const bf16x8*)(&lds16[t][T * 32 + q * 8]);
      *(bf16x8*)(Apack + (((long)(R * 32 + T) * 4 + s3) * 64 + l) * 8) = val;
    }
    __syncthreads();
  }
}

// ---- kernel 2: barrier-free GEMM + tanh/v-dot epilogue.
// 4 waves/block (wc=wave), each wave: rows blk*64..+64, n=wc*128..+128.
// All operands fragment-packed in global; 2-deep register prefetch;
// no LDS / no barriers in the loop -> waves free-run.
__global__ __launch_bounds__(256, 2) void gemm_score(
    const __bf16* __restrict__ Apack, // packed A, 128 MB
    const __bf16* __restrict__ Bp,    // packed B, 1 MB
    const float* __restrict__ hproj,  // [64][512]
    const float* __restrict__ v,      // [512]
    float* __restrict__ scores)       // [64][1024]  ([b][s])
{
  __shared__ float bscore[64];

  const int tid  = threadIdx.x;
  const int lane = tid & 63;
  const int wc   = tid >> 6;      // wave -> n-range [wc*128, wc*128+128)
  const int q    = lane >> 4;
  const int t    = lane & 15;

  if (tid < 64) bscore[tid] = 0.f;
  __syncthreads();                // once, before any loads are in flight

  // per-lane fragment bases (elements)
  const __bf16* apb = Apack + ((long)blockIdx.x * 128 + lane) * 8 * 16;
  // chunk (T,rt) at apb + ((long)T*4 + rt)*512 ... note 128*16*8? recompute:
  // chunk index = (blk*32 + T)*4 + rt; elem = chunk*512 + lane*8
  const __bf16* apbase = Apack + (long)blockIdx.x * 32 * 4 * 512 + (long)lane * 8;
  const __bf16* bpbase = Bp + (long)wc * 4096 + (long)lane * 8;

  floatx4 acc[4][8];
  #pragma unroll
  for (int i = 0; i < 4; i++)
    #pragma unroll
    for (int j = 0; j < 8; j++)
      acc[i][j] = (floatx4){0.f, 0.f, 0.f, 0.f};

  short8 afr[2][4];
  short8 bfr[2][8];

  auto issueP = [&](int T, int s) {
    #pragma unroll
    for (int rt = 0; rt < 4; rt++) {
      union bfu u;
      u.v = *(const bf16x8*)(apbase + ((long)T * 4 + rt) * 512);
      afr[s][rt] = u.s;
    }
    #pragma unroll
    for (int ct = 0; ct < 8; ct++) {
      union bfu u;
      u.v = *(const bf16x8*)(bpbase + (long)T * 16384 + ct * 512);
      bfr[s][ct] = u.s;
    }
  };
  auto computeP = [&](int s) {
    #pragma unroll
    for (int rt = 0; rt < 4; rt++)
      #pragma unroll
      for (int ct = 0; ct < 8; ct++)
        acc[rt][ct] = __builtin_amdgcn_mfma_f32_16x16x32_bf16(
            afr[s][rt], bfr[s][ct], acc[rt][ct], 0, 0, 0);
  };

  (void)apb;
  // prologue: 2 k-steps in flight
  issueP(0, 0);
  issueP(1, 1);

#define PHASE(T)                                           \
  {                                                        \
    computeP((T) & 1);                                     \
    SB();                                                  \
    if ((T) < 30) issueP((T) + 2, (T) & 1);                \
    SB();                                                  \
  }

  PHASE(0)  PHASE(1)  PHASE(2)  PHASE(3)
  PHASE(4)  PHASE(5)  PHASE(6)  PHASE(7)
  PHASE(8)  PHASE(9)  PHASE(10) PHASE(11)
  PHASE(12) PHASE(13) PHASE(14) PHASE(15)
  PHASE(16) PHASE(17) PHASE(18) PHASE(19)
  PHASE(20) PHASE(21) PHASE(22) PHASE(23)
  PHASE(24) PHASE(25) PHASE(26) PHASE(27)
  PHASE(28) PHASE(29) PHASE(30) PHASE(31)
#undef PHASE

  // ---- epilogue: score[row] = sum_n v[n] * tanh(acc + hproj[row][n])
  // rows 0..63 of this block: global m = blk*64+row = s*64+b -> s=blk, b=row.
  float vv[8];
  #pragma unroll
  for (int ct = 0; ct < 8; ct++) vv[ct] = v[wc * 128 + ct * 16 + t];

  #pragma unroll
  for (int rt = 0; rt < 4; rt++) {
    #pragma unroll
    for (int r = 0; r < 4; r++) {
      int row = rt * 16 + q * 4 + r;              // C/D: row=(lane>>4)*4+reg
      const float* hrow = hproj + row * 512 + wc * 128 + t;
      float s = 0.f;
      #pragma unroll
      for (int ct = 0; ct < 8; ct++) {
        float e  = acc[rt][ct][r] + hrow[ct * 16];
        float ex = __builtin_amdgcn_exp2f(e * LOG2E_X2);        // e^(2x)
        float th = 1.f - 2.f * __builtin_amdgcn_rcpf(ex + 1.f); // tanh(x)
        s = fmaf(vv[ct], th, s);
      }
      s += __shfl_xor(s, 1);
      s += __shfl_xor(s, 2);
      s += __shfl_xor(s, 4);
      s += __shfl_xor(s, 8);
      if (t == 0) atomicAdd(&bscore[row], s);
    }
  }
  __syncthreads();
  if (tid < 64) scores[(long)tid * 1024 + blockIdx.x] = bscore[tid];
}

// ---- kernel 3: softmax over s for each b
__global__ void softmax_kernel(const float* __restrict__ scores,
                               float* __restrict__ out) {
  const int b_   = blockIdx.x;
  const int tid  = threadIdx.x;
  const int lane = tid & 63;
  const int wv   = tid >> 6;
  __shared__ float redmax[4], redsum[4];

  float x[4];
  #pragma unroll
  for (int i = 0; i < 4; i++) x[i] = scores[b_ * 1024 + i * 256 + tid];
  float mx = fmaxf(fmaxf(x[0], x[1]), fmaxf(x[2], x[3]));
  #pragma unroll
  for (int off = 1; off < 64; off <<= 1) mx = fmaxf(mx, __shfl_xor(mx, off));
  if (lane == 0) redmax[wv] = mx;
  __syncthreads();
  mx = fmaxf(fmaxf(redmax[0], redmax[1]), fmaxf(redmax[2], redmax[3]));

  float e[4], s = 0.f;
  #pragma unroll
  for (int i = 0; i < 4; i++) { e[i] = __expf(x[i] - mx); s += e[i]; }
  #pragma unroll
  for (int off = 1; off < 64; off <<= 1) s += __shfl_xor(s, off);
  if (lane == 0) redsum[wv] = s;
  __syncthreads();
  s = redsum[0] + redsum[1] + redsum[2] + redsum[3];
  float inv = 1.f / s;
  #pragma unroll
  for (int i = 0; i < 4; i++) out[b_ * 1024 + i * 256 + tid] = e[i] * inv;
}

extern "C" void kernel_launch(void* const* d_in, const int* in_sizes, int n_in,
                              void* d_out, int out_size, void* d_ws, size_t ws_size,
                              hipStream_t stream) {
  (void)in_sizes; (void)n_in; (void)out_size; (void)ws_size;
  const float* hidden = (const float*)d_in[0];   // [64,512]
  const float* enc    = (const float*)d_in[1];   // [1024,64,1024]
  const float* W      = (const float*)d_in[2];   // [1536,512]
  const float* bias   = (const float*)d_in[3];   // [512]
  const float* v      = (const float*)d_in[4];   // [512]
  float* out = (float*)d_out;                    // [64,1024]

  char* ws = (char*)d_ws;
  __bf16* Bp    = (__bf16*)ws;                            // 1 MB (packed B)
  float*  hproj = (float*)(ws + (1 << 20));               // 128 KB
  float*  scores= (float*)(ws + (1 << 20) + (128 << 10)); // 256 KB
  __bf16* Apack = (__bf16*)(ws + (2 << 20));              // 128 MB (packed A)

  hipMemsetAsync(hproj, 0, 64 * 512 * sizeof(float), stream);
  wt_convert<<<128, 256, 0, stream>>>(W, Bp);
  hproj_kernel<<<256, 512, 0, stream>>>(hidden, W, bias, hproj);
  aconv_kernel<<<1024, 256, 0, stream>>>(enc, Apack);
  gemm_score<<<1024, 256, 0, stream>>>(Apack, Bp, hproj, v, scores);
  softmax_kernel<<<64, 256, 0, stream>>>(scores, out);
}

// Round 8
// 470.850 us; speedup vs baseline: 1.0315x; 1.0315x over previous
//
#include <hip/hip_runtime.h>
#include <stdint.h>

// ---------------------------------------------------------------------------
// scores[b,s] = v . tanh( hidden[b] @ Wh + bias + enc[s,b] @ We )
// out[b,s]   = softmax_s(scores)
// Big GEMM: enc_flat[M=65536,K=1024] @ We[K=1024,N=512], bf16 MFMA.
// R9: the wall (R4 counters) is the A-stream running at 780 GB/s (12% of
//     achievable) -- outstanding-byte starved, not barrier/conflict/occ
//     bound (R8 falsified the barrier theory). Fix = deep async staging:
//     A via global_load_lds(16B) into an 8-deep LDS ring (56KB/block in
//     flight, no VGPR cost), fp32->bf16 cvt at fragment read. Counted
//     vmcnt only (never drained); one raw lgkm-barrier per phase.
//     Read conflicts: pre-swizzled SOURCE (chunk s^(r&7)) + same XOR on
//     ds_read addr; gl_lds dest stays linear (rule #21).
//     B stays packed fragment-order register loads (R5), 2-deep.
// ---------------------------------------------------------------------------

typedef float  floatx4 __attribute__((ext_vector_type(4)));
typedef __bf16 bf16x8  __attribute__((ext_vector_type(8)));
typedef short  short8  __attribute__((ext_vector_type(8)));

union bfu { bf16x8 v; short8 s; };

#define LOG2E_X2 2.8853900817779268f
#define SB() __builtin_amdgcn_sched_barrier(0)

// raw barrier: wait own LDS reads only; global/async loads ride across.
#define BAR()                                              \
  do {                                                     \
    asm volatile("s_waitcnt lgkmcnt(0)" ::: "memory");     \
    SB();                                                  \
    __builtin_amdgcn_s_barrier();                          \
    SB();                                                  \
  } while (0)

__device__ __forceinline__ void async_ld16(const void* g, void* l) {
  __builtin_amdgcn_global_load_lds(
      (const __attribute__((address_space(1))) void*)g,
      (__attribute__((address_space(3))) void*)l, 16, 0, 0);
}

// ---- kernel 0: W[512:1536,:] -> fragment-packed bf16 B.
// Bp frag(T,wc,ct) base elem = ((T*4+wc)*8+ct)*512; lane (q*16+t) holds 8 k.
__global__ void wt_convert(const float* __restrict__ W, __bf16* __restrict__ Bp) {
  __shared__ float tile[64][65];                 // +1 pad: conflict-free both ways
  const int kt = blockIdx.x >> 3;                // 16 k-tiles (64 k each)
  const int nt = blockIdx.x & 7;                 // 8 n-tiles (64 n each)
  const int c  = threadIdx.x & 63;
  const int r4 = threadIdx.x >> 6;               // 4 rows per pass
  #pragma unroll 4
  for (int i = 0; i < 16; i++) {
    int r = i * 4 + r4;                          // k-local
    tile[r][c] = W[(long)(512 + kt * 64 + r) * 512 + nt * 64 + c];
  }
  __syncthreads();
  const int n_loc = threadIdx.x & 63;
  const int kc4   = threadIdx.x >> 6;            // 0..3
  const int n_g   = nt * 64 + n_loc;
  const int wc    = n_g >> 7;
  const int ct    = (n_g >> 4) & 7;
  const int t     = n_g & 15;
  #pragma unroll
  for (int i = 0; i < 2; i++) {
    int chunk = i * 4 + kc4;                     // k_loc = chunk*8 + j
    int k_g   = kt * 64 + chunk * 8;
    int T     = k_g >> 5;
    int q     = (k_g >> 3) & 3;
    union bfu u;
    #pragma unroll
    for (int j = 0; j < 8; j++) u.v[j] = (__bf16)tile[chunk * 8 + j][n_loc];
    long cidx = ((long)(T * 4 + wc) * 8 + ct) * 64 + q * 16 + t;
    *(bf16x8*)(Bp + cidx * 8) = u.v;
  }
}

// ---- kernel 1: hproj[b][n] = bias[n] + sum_k hidden[b,k] * W[k,n]  (k<512)
__global__ void hproj_kernel(const float* __restrict__ hidden,
                             const float* __restrict__ W,
                             const float* __restrict__ bias,
                             float* __restrict__ hproj) {
  const int tid = threadIdx.x;            // n
  const int b_  = blockIdx.x >> 2;
  const int kc  = blockIdx.x & 3;
  __shared__ float hid[128];
  if (tid < 128) hid[tid] = hidden[b_ * 512 + kc * 128 + tid];
  __syncthreads();
  float acc = (kc == 0) ? bias[tid] : 0.f;
  const float* Wp = W + (long)(kc * 128) * 512 + tid;
  #pragma unroll 8
  for (int k = 0; k < 128; k++) acc = fmaf(hid[k], Wp[(long)k * 512], acc);
  atomicAdd(&hproj[b_ * 512 + tid], acc);
}

// ---- kernel 2: GEMM + tanh/v-dot epilogue; deep-async A ring.
// Block: 256 thr / 4 waves; tile 64 rows x full N=512 (wave wc: n=wc*128..).
// A: fp32 tiles 64x32 in an 8-buf LDS ring via global_load_lds.
//   LDS layout (floats): buf[T&7], addr = r*32 + slot*4 + j, slot = chunk ^ (r&7)
//   (chunk = 16B-group of 4 floats; XOR spreads the column read across 8
//    slots -> 2 lanes/slot = free).  gl_lds dest is LINEAR (L*16B); the
//   permutation is applied to the SOURCE address instead.
__global__ __launch_bounds__(256) void gemm_score(
    const float* __restrict__ enc,    // [65536][1024] fp32
    const __bf16* __restrict__ Bp,    // packed B, 1 MB
    const float* __restrict__ hproj,  // [64][512]
    const float* __restrict__ v,      // [512]
    float* __restrict__ scores)       // [64][1024]  ([b][s])
{
  __shared__ float ldsA[8][2048];    // 8 bufs x (64 rows x 32 floats) = 64 KB
  __shared__ float bscore[64];

  const int tid  = threadIdx.x;
  const int lane = tid & 63;
  const int wc   = tid >> 6;      // wave -> n-range [wc*128, wc*128+128)
  const int q    = lane >> 4;
  const int t    = lane & 15;
  const long m0  = (long)blockIdx.x * 64;

  // staging: load index L = i*256 + tid (i=0,1): r = L>>3, dest slot s = L&7,
  // source chunk = s ^ (r&7). dest lds float-offset = L*4 (linear, 16B/load).
  const int r0 = tid >> 3, s0 = tid & 7;
  const int r1 = r0 + 32;
  const float* src0 = enc + (m0 + r0) * 1024 + ((s0 ^ (r0 & 7)) << 2);
  const float* src1 = enc + (m0 + r1) * 1024 + ((s0 ^ (r1 & 7)) << 2);
  const int d0 = tid * 4;            // float offset in buf
  const int d1 = 1024 + tid * 4;

  // packed-B per-lane base: frag(T,ct) at + T*16384 + ct*512 elems
  const __bf16* bpb = Bp + (long)wc * 4096 + (long)lane * 8;

  if (tid < 64) bscore[tid] = 0.f;

  floatx4 acc[4][8];
  #pragma unroll
  for (int i = 0; i < 4; i++)
    #pragma unroll
    for (int j = 0; j < 8; j++)
      acc[i][j] = (floatx4){0.f, 0.f, 0.f, 0.f};

  short8 bfr[2][8];    // B fragments, double buffered

  auto stage = [&](int T) {          // 2 async 16B loads -> ring buf T&7
    float* db = &ldsA[T & 7][0];
    async_ld16(src0 + T * 32, db + d0);
    async_ld16(src1 + T * 32, db + d1);
  };
  auto loadB = [&](int T, int s) {   // 8 coalesced 1KB wave-loads (L2)
    #pragma unroll
    for (int ct = 0; ct < 8; ct++) {
      union bfu u;
      u.v = *(const bf16x8*)(bpb + (long)T * 16384 + ct * 512);
      bfr[s][ct] = u.s;
    }
  };
  auto compute = [&](int T, int bs) {
    const float* bb = &ldsA[T & 7][0];
    #pragma unroll
    for (int rt = 0; rt < 4; rt++) {
      const int r = rt * 16 + t;                     // r&7 == t&7
      floatx4 f0 = *(const floatx4*)(bb + r * 32 + (((2 * q)     ^ (t & 7)) << 2));
      floatx4 f1 = *(const floatx4*)(bb + r * 32 + (((2 * q + 1) ^ (t & 7)) << 2));
      union bfu u;
      #pragma unroll
      for (int j = 0; j < 4; j++) {
        u.v[j]     = (__bf16)f0[j];
        u.v[4 + j] = (__bf16)f1[j];
      }
      #pragma unroll
      for (int ct = 0; ct < 8; ct++)
        acc[rt][ct] = __builtin_amdgcn_mfma_f32_16x16x32_bf16(
            u.s, bfr[bs][ct], acc[rt][ct], 0, 0, 0);
    }
  };

  // prologue: 7 A-tiles in flight (14 gl_lds), B0/B1 in regs.
  stage(0); stage(1); stage(2); stage(3); stage(4); stage(5); stage(6);
  loadB(0, 0); loadB(1, 1);
  // retire the 14 stage loads (16 younger B-loads may remain in flight)
  asm volatile("s_waitcnt vmcnt(16)" ::: "memory");
  SB();
  __builtin_amdgcn_s_barrier();
  SB();

  // Phase T: BAR (WAR: buf[(T+7)&7] == buf[(T-1)&7], read last phase);
  //   stage(T+7) async; compute(T) (compiler waits: lgkm for ds_read,
  //   counted vmcnt for bfr(T) -- issued 2 phases ago; in-order retirement
  //   means that wait also confirms stage(T+5), so tile T is long-landed);
  //   loadB(T+2) refills the set compute just consumed.
#define PHASE(T)                                           \
  {                                                        \
    if ((T) > 0) BAR();                                    \
    if ((T) < 25) stage((T) + 7);                          \
    compute((T), (T) & 1);                                 \
    if ((T) < 30) loadB((T) + 2, (T) & 1);                 \
  }

  PHASE(0)  PHASE(1)  PHASE(2)  PHASE(3)
  PHASE(4)  PHASE(5)  PHASE(6)  PHASE(7)
  PHASE(8)  PHASE(9)  PHASE(10) PHASE(11)
  PHASE(12) PHASE(13) PHASE(14) PHASE(15)
  PHASE(16) PHASE(17) PHASE(18) PHASE(19)
  PHASE(20) PHASE(21) PHASE(22) PHASE(23)
  PHASE(24) PHASE(25) PHASE(26) PHASE(27)
  PHASE(28) PHASE(29) PHASE(30) PHASE(31)
#undef PHASE

  // ---- epilogue: score[row] = sum_n v[n] * tanh(acc + hproj[row][n])
  // rows 0..63: global m = blk*64+row = s*64+b -> s=blk, b=row.
  float vv[8];
  #pragma unroll
  for (int ct = 0; ct < 8; ct++) vv[ct] = v[wc * 128 + ct * 16 + t];

  #pragma unroll
  for (int rt = 0; rt < 4; rt++) {
    #pragma unroll
    for (int r = 0; r < 4; r++) {
      int row = rt * 16 + q * 4 + r;              // C/D: row=(lane>>4)*4+reg
      const float* hrow = hproj + row * 512 + wc * 128 + t;
      float s = 0.f;
      #pragma unroll
      for (int ct = 0; ct < 8; ct++) {
        float e  = acc[rt][ct][r] + hrow[ct * 16];
        float ex = __builtin_amdgcn_exp2f(e * LOG2E_X2);        // e^(2x)
        float th = 1.f - 2.f * __builtin_amdgcn_rcpf(ex + 1.f); // tanh(x)
        s = fmaf(vv[ct], th, s);
      }
      s += __shfl_xor(s, 1);
      s += __shfl_xor(s, 2);
      s += __shfl_xor(s, 4);
      s += __shfl_xor(s, 8);
      if (t == 0) atomicAdd(&bscore[row], s);
    }
  }
  __syncthreads();   // once, end of kernel
  if (tid < 64) scores[(long)tid * 1024 + blockIdx.x] = bscore[tid];
}

// ---- kernel 3: softmax over s for each b
__global__ void softmax_kernel(const float* __restrict__ scores,
                               float* __restrict__ out) {
  const int b_   = blockIdx.x;
  const int tid  = threadIdx.x;
  const int lane = tid & 63;
  const int wv   = tid >> 6;
  __shared__ float redmax[4], redsum[4];

  float x[4];
  #pragma unroll
  for (int i = 0; i < 4; i++) x[i] = scores[b_ * 1024 + i * 256 + tid];
  float mx = fmaxf(fmaxf(x[0], x[1]), fmaxf(x[2], x[3]));
  #pragma unroll
  for (int off = 1; off < 64; off <<= 1) mx = fmaxf(mx, __shfl_xor(mx, off));
  if (lane == 0) redmax[wv] = mx;
  __syncthreads();
  mx = fmaxf(fmaxf(redmax[0], redmax[1]), fmaxf(redmax[2], redmax[3]));

  float e[4], s = 0.f;
  #pragma unroll
  for (int i = 0; i < 4; i++) { e[i] = __expf(x[i] - mx); s += e[i]; }
  #pragma unroll
  for (int off = 1; off < 64; off <<= 1) s += __shfl_xor(s, off);
  if (lane == 0) redsum[wv] = s;
  __syncthreads();
  s = redsum[0] + redsum[1] + redsum[2] + redsum[3];
  float inv = 1.f / s;
  #pragma unroll
  for (int i = 0; i < 4; i++) out[b_ * 1024 + i * 256 + tid] = e[i] * inv;
}

extern "C" void kernel_launch(void* const* d_in, const int* in_sizes, int n_in,
                              void* d_out, int out_size, void* d_ws, size_t ws_size,
                              hipStream_t stream) {
  (void)in_sizes; (void)n_in; (void)out_size; (void)ws_size;
  const float* hidden = (const float*)d_in[0];   // [64,512]
  const float* enc    = (const float*)d_in[1];   // [1024,64,1024]
  const float* W      = (const float*)d_in[2];   // [1536,512]
  const float* bias   = (const float*)d_in[3];   // [512]
  const float* v      = (const float*)d_in[4];   // [512]
  float* out = (float*)d_out;                    // [64,1024]

  char* ws = (char*)d_ws;
  __bf16* Bp    = (__bf16*)ws;                            // 1 MB (packed B)
  float*  hproj = (float*)(ws + (1 << 20));               // 128 KB
  float*  scores= (float*)(ws + (1 << 20) + (128 << 10)); // 256 KB

  hipMemsetAsync(hproj, 0, 64 * 512 * sizeof(float), stream);
  wt_convert<<<128, 256, 0, stream>>>(W, Bp);
  hproj_kernel<<<256, 512, 0, stream>>>(hidden, W, bias, hproj);
  gemm_score<<<1024, 256, 0, stream>>>(enc, Bp, hproj, v, scores);
  softmax_kernel<<<64, 256, 0, stream>>>(scores, out);
}

// Round 9
// 468.861 us; speedup vs baseline: 1.0359x; 1.0042x over previous
//
#include <hip/hip_runtime.h>
#include <stdint.h>

// ---------------------------------------------------------------------------
// scores[b,s] = v . tanh( hidden[b] @ Wh + bias + enc[s,b] @ We )
// out[b,s]   = softmax_s(scores)
// Big GEMM: enc_flat[M=65536,K=1024] @ We[K=1024,N=512], bf16 MFMA.
// R10: occupancy fix, done right this time. R6-R9 falsified BW/conflict/
//     barrier theories; every variant had <=2 waves/SIMD in ONE barrier
//     group (acc[4][8]+bfr = 256 unified regs, or 64KB LDS) -> zero TLP to
//     hide the per-phase latency chain. m97-class kernels run ~3 indep
//     blocks/CU. Now: 256 thr / 4 waves, tile 32 rows x N=512, grid 2048;
//     per-wave 32x128 -> acc[2][8]=64 AGPR + bfr[8]=32 + ra 12 ~ 135 regs
//     -> 3 waves/SIMD = 3 independent blocks/CU. NO launch_bounds cap
//     beyond block size (R6 spill lesson).
//     Keeps: packed fragment-order B (R5), XOR-swizzled bf16 A LDS
//     (quarter-wave-verified conflict-free), raw lgkm-only barriers (R4),
//     compute -> writeA -> loadB -> issueA order (R6).
// ---------------------------------------------------------------------------

typedef float  floatx4 __attribute__((ext_vector_type(4)));
typedef __bf16 bf16x4  __attribute__((ext_vector_type(4)));
typedef __bf16 bf16x8  __attribute__((ext_vector_type(8)));
typedef short  short8  __attribute__((ext_vector_type(8)));

union bfu  { bf16x8 v; short8 s; };
union bfu4 { bf16x4 v; uint2 u; };

#define LOG2E_X2 2.8853900817779268f

// raw barrier: wait own LDS ops only; global prefetches ride across.
#define BAR()                                              \
  do {                                                     \
    asm volatile("s_waitcnt lgkmcnt(0)" ::: "memory");     \
    __builtin_amdgcn_sched_barrier(0);                     \
    __builtin_amdgcn_s_barrier();                          \
    __builtin_amdgcn_sched_barrier(0);                     \
  } while (0)

#define SB() __builtin_amdgcn_sched_barrier(0)

// ---- kernel 0: W[512:1536,:] -> fragment-packed bf16 B.
// Bp frag(T,wc,ct) base elem = ((T*4+wc)*8+ct)*512; lane (q*16+t) holds 8 k.
__global__ void wt_convert(const float* __restrict__ W, __bf16* __restrict__ Bp) {
  __shared__ float tile[64][65];                 // +1 pad: conflict-free both ways
  const int kt = blockIdx.x >> 3;                // 16 k-tiles (64 k each)
  const int nt = blockIdx.x & 7;                 // 8 n-tiles (64 n each)
  const int c  = threadIdx.x & 63;
  const int r4 = threadIdx.x >> 6;               // 4 rows per pass
  #pragma unroll 4
  for (int i = 0; i < 16; i++) {
    int r = i * 4 + r4;                          // k-local
    tile[r][c] = W[(long)(512 + kt * 64 + r) * 512 + nt * 64 + c];
  }
  __syncthreads();
  const int n_loc = threadIdx.x & 63;
  const int kc4   = threadIdx.x >> 6;            // 0..3
  const int n_g   = nt * 64 + n_loc;
  const int wc    = n_g >> 7;
  const int ct    = (n_g >> 4) & 7;
  const int t     = n_g & 15;
  #pragma unroll
  for (int i = 0; i < 2; i++) {
    int chunk = i * 4 + kc4;                     // k_loc = chunk*8 + j
    int k_g   = kt * 64 + chunk * 8;
    int T     = k_g >> 5;
    int q     = (k_g >> 3) & 3;
    union bfu u;
    #pragma unroll
    for (int j = 0; j < 8; j++) u.v[j] = (__bf16)tile[chunk * 8 + j][n_loc];
    long cidx = ((long)(T * 4 + wc) * 8 + ct) * 64 + q * 16 + t;
    *(bf16x8*)(Bp + cidx * 8) = u.v;
  }
}

// ---- kernel 1: hproj[b][n] = bias[n] + sum_k hidden[b,k] * W[k,n]  (k<512)
__global__ void hproj_kernel(const float* __restrict__ hidden,
                             const float* __restrict__ W,
                             const float* __restrict__ bias,
                             float* __restrict__ hproj) {
  const int tid = threadIdx.x;            // n
  const int b_  = blockIdx.x >> 2;
  const int kc  = blockIdx.x & 3;
  __shared__ float hid[128];
  if (tid < 128) hid[tid] = hidden[b_ * 512 + kc * 128 + tid];
  __syncthreads();
  float acc = (kc == 0) ? bias[tid] : 0.f;
  const float* Wp = W + (long)(kc * 128) * 512 + tid;
  #pragma unroll 8
  for (int k = 0; k < 128; k++) acc = fmaf(hid[k], Wp[(long)k * 512], acc);
  atomicAdd(&hproj[b_ * 512 + tid], acc);
}

// ---- kernel 2: GEMM + tanh/v-dot epilogue; 32-row tiles, 3 blocks/CU.
__global__ __launch_bounds__(256) void gemm_score(
    const float* __restrict__ enc,    // [65536][1024] fp32
    const __bf16* __restrict__ Bp,    // packed B, 1 MB
    const float* __restrict__ hproj,  // [64][512]
    const float* __restrict__ v,      // [512]
    float* __restrict__ scores)       // [64][1024]  ([b][s])
{
  // bf16 A tile 32m x 32k, double buffered (2KB each).
  //   elem addr = c*256 + ((m*8) ^ (c*16)) + j   (c=k/8 in 0..3, j=k%8)
  __shared__ __bf16 ldsA[2][1024];
  __shared__ float bscore[32];

  const int tid  = threadIdx.x;
  const int lane = tid & 63;
  const int wc   = tid >> 6;      // wave -> n-range [wc*128, wc*128+128)
  const int q    = lane >> 4;
  const int t    = lane & 15;
  const long m0  = (long)blockIdx.x * 32;

  // staging: thread -> row m = tid>>3 (0..31), k-quad kq = tid&7; 16B/thread
  const int m  = tid >> 3;
  const int kq = tid & 7;
  const int c_ = kq >> 1;
  const int jh = (kq & 1) * 4;
  const float* ap = enc + (m0 + m) * 1024 + kq * 4;
  __bf16* aw0 = &ldsA[0][c_ * 256 + ((m * 8) ^ (c_ * 16)) + jh]; // ds_write_b64
  __bf16* aw1 = &ldsA[1][c_ * 256 + ((m * 8) ^ (c_ * 16)) + jh];

  // fragment read base: lane (q,t), rt -> A[rt*16 + t][q*8..q*8+7]
  // addr = q*256 + rt*128 + ((t*8) ^ (q*16))
  const __bf16* ar0 = &ldsA[0][q * 256 + ((t * 8) ^ (q * 16))];
  const __bf16* ar1 = &ldsA[1][q * 256 + ((t * 8) ^ (q * 16))];

  // packed-B per-lane base: frag(T,ct) at + T*16384 + ct*512 elems
  const __bf16* bpb = Bp + (long)wc * 4096 + (long)lane * 8;

  if (tid < 32) bscore[tid] = 0.f;

  floatx4 acc[2][8];
  #pragma unroll
  for (int i = 0; i < 2; i++)
    #pragma unroll
    for (int j = 0; j < 8; j++)
      acc[i][j] = (floatx4){0.f, 0.f, 0.f, 0.f};

  floatx4 ra[3];       // A staging regs: 3 k-steps in flight, 16B each
  short8  bfr[8];      // B fragments, single buffer (TLP covers L2 latency)

  auto issueA = [&](int T, int s) {          // global fp32 -> reg (no wait)
    ra[s] = *(const floatx4*)(ap + T * 32);
  };
  auto writeA = [&](int s, __bf16* dst) {    // cvt once + 8B ds_write
    union bfu4 u;
    #pragma unroll
    for (int j = 0; j < 4; j++) u.v[j] = (__bf16)ra[s][j];
    *(bf16x4*)dst = u.v;
  };
  auto loadB = [&](int T) {                  // 8 coalesced 1KB wave-loads
    #pragma unroll
    for (int ct = 0; ct < 8; ct++) {
      union bfu u;
      u.v = *(const bf16x8*)(bpb + (long)T * 16384 + ct * 512);
      bfr[ct] = u.s;
    }
  };
  auto compute = [&](const __bf16* base) {
    #pragma unroll
    for (int rt = 0; rt < 2; rt++) {
      union bfu u;
      u.v = *(const bf16x8*)(base + rt * 128);   // 1 ds_read_b128 per rt
      #pragma unroll
      for (int ct = 0; ct < 8; ct++)
        acc[rt][ct] = __builtin_amdgcn_mfma_f32_16x16x32_bf16(
            u.s, bfr[ct], acc[rt][ct], 0, 0, 0);
    }
  };

  // prologue: A0..A2 in flight, B0 in regs, stage A0 into buf0
  issueA(0, 0); issueA(1, 1); issueA(2, 2);
  loadB(0);
  writeA(0, aw0);               // compiler waits vmcnt for A0 only
  BAR();

  // Phase T: compute A(T) from buf(T&1) with B(T)=bfr;
  //   then writeA(T+1) (its load is 2 phases old); then loadB(T+1)
  //   (refills bfr, consumed next phase); issueA(T+3) LAST so B stays
  //   older than the next HBM A load. Raw barrier: lgkm only.
#define PHASE(T)                                           \
  {                                                        \
    compute(((T) & 1) ? ar1 : ar0);                        \
    SB();                                                  \
    if ((T) < 31) writeA(((T) + 1) % 3, ((T) & 1) ? aw0 : aw1); \
    if ((T) < 31) loadB((T) + 1);                          \
    SB();                                                  \
    if ((T) < 29) issueA((T) + 3, (T) % 3);                \
    BAR();                                                 \
  }

  PHASE(0)  PHASE(1)  PHASE(2)  PHASE(3)
  PHASE(4)  PHASE(5)  PHASE(6)  PHASE(7)
  PHASE(8)  PHASE(9)  PHASE(10) PHASE(11)
  PHASE(12) PHASE(13) PHASE(14) PHASE(15)
  PHASE(16) PHASE(17) PHASE(18) PHASE(19)
  PHASE(20) PHASE(21) PHASE(22) PHASE(23)
  PHASE(24) PHASE(25) PHASE(26) PHASE(27)
  PHASE(28) PHASE(29) PHASE(30) PHASE(31)
#undef PHASE

  // ---- epilogue: score = sum_n v[n] * tanh(acc + hproj[b][n])
  // global m = blk*32 + row = s*64 + b -> s = blk>>1, b = (blk&1)*32 + row.
  float vv[8];
  #pragma unroll
  for (int ct = 0; ct < 8; ct++) vv[ct] = v[wc * 128 + ct * 16 + t];

  const int bbase = (blockIdx.x & 1) * 32;
  #pragma unroll
  for (int rt = 0; rt < 2; rt++) {
    #pragma unroll
    for (int r = 0; r < 4; r++) {
      int row = rt * 16 + q * 4 + r;              // 0..31
      const float* hrow = hproj + (bbase + row) * 512 + wc * 128 + t;
      float s = 0.f;
      #pragma unroll
      for (int ct = 0; ct < 8; ct++) {
        float e  = acc[rt][ct][r] + hrow[ct * 16];
        float ex = __builtin_amdgcn_exp2f(e * LOG2E_X2);        // e^(2x)
        float th = 1.f - 2.f * __builtin_amdgcn_rcpf(ex + 1.f); // tanh(x)
        s = fmaf(vv[ct], th, s);
      }
      s += __shfl_xor(s, 1);
      s += __shfl_xor(s, 2);
      s += __shfl_xor(s, 4);
      s += __shfl_xor(s, 8);
      if (t == 0) atomicAdd(&bscore[row], s);
    }
  }
  __syncthreads();   // once, end of kernel
  if (tid < 32)
    scores[(long)(bbase + tid) * 1024 + (blockIdx.x >> 1)] = bscore[tid];
}

// ---- kernel 3: softmax over s for each b
__global__ void softmax_kernel(const float* __restrict__ scores,
                               float* __restrict__ out) {
  const int b_   = blockIdx.x;
  const int tid  = threadIdx.x;
  const int lane = tid & 63;
  const int wv   = tid >> 6;
  __shared__ float redmax[4], redsum[4];

  float x[4];
  #pragma unroll
  for (int i = 0; i < 4; i++) x[i] = scores[b_ * 1024 + i * 256 + tid];
  float mx = fmaxf(fmaxf(x[0], x[1]), fmaxf(x[2], x[3]));
  #pragma unroll
  for (int off = 1; off < 64; off <<= 1) mx = fmaxf(mx, __shfl_xor(mx, off));
  if (lane == 0) redmax[wv] = mx;
  __syncthreads();
  mx = fmaxf(fmaxf(redmax[0], redmax[1]), fmaxf(redmax[2], redmax[3]));

  float e[4], s = 0.f;
  #pragma unroll
  for (int i = 0; i < 4; i++) { e[i] = __expf(x[i] - mx); s += e[i]; }
  #pragma unroll
  for (int off = 1; off < 64; off <<= 1) s += __shfl_xor(s, off);
  if (lane == 0) redsum[wv] = s;
  __syncthreads();
  s = redsum[0] + redsum[1] + redsum[2] + redsum[3];
  float inv = 1.f / s;
  #pragma unroll
  for (int i = 0; i < 4; i++) out[b_ * 1024 + i * 256 + tid] = e[i] * inv;
}

extern "C" void kernel_launch(void* const* d_in, const int* in_sizes, int n_in,
                              void* d_out, int out_size, void* d_ws, size_t ws_size,
                              hipStream_t stream) {
  (void)in_sizes; (void)n_in; (void)out_size; (void)ws_size;
  const float* hidden = (const float*)d_in[0];   // [64,512]
  const float* enc    = (const float*)d_in[1];   // [1024,64,1024]
  const float* W      = (const float*)d_in[2];   // [1536,512]
  const float* bias   = (const float*)d_in[3];   // [512]
  const float* v      = (const float*)d_in[4];   // [512]
  float* out = (float*)d_out;                    // [64,1024]

  char* ws = (char*)d_ws;
  __bf16* Bp    = (__bf16*)ws;                            // 1 MB (packed B)
  float*  hproj = (float*)(ws + (1 << 20));               // 128 KB
  float*  scores= (float*)(ws + (1 << 20) + (128 << 10)); // 256 KB

  hipMemsetAsync(hproj, 0, 64 * 512 * sizeof(float), stream);
  wt_convert<<<128, 256, 0, stream>>>(W, Bp);
  hproj_kernel<<<256, 512, 0, stream>>>(hidden, W, bias, hproj);
  gemm_score<<<2048, 256, 0, stream>>>(enc, Bp, hproj, v, scores);
  softmax_kernel<<<64, 256, 0, stream>>>(scores, out);
}

// Round 10
// 419.503 us; speedup vs baseline: 1.1578x; 1.1177x over previous
//
#include <hip/hip_runtime.h>
#include <stdint.h>

// ---------------------------------------------------------------------------
// scores[b,s] = v . tanh( hidden[b] @ Wh + bias + enc[s,b] @ We )
// out[b,s]   = softmax_s(scores)
// Big GEMM: enc_flat[M=65536,K=1024] @ We[K=1024,N=512], bf16 MFMA.
// R11: DRAM-efficiency + amortization fix. All enc-strip variants pinned at
//     ~790 GB/s HBM (128-B touches at 4-KB stride = row-activation thrash);
//     and 32-MFMA phases beat 16-MFMA (R5 139 vs R10 190). Now BK=128
//     mega-phases: 512-B contiguous per row per phase (4x DRAM chunk),
//     128 MFMA + 1 barrier per phase (8 barriers vs 32), B rolling
//     1-step-ahead. Register envelope = R5's proven class (arch ~116 +
//     128 AGPR <= 256 under launch_bounds(256,2)).
//     Keeps: packed fragment-order B (R5), XOR-swizzled bf16 A LDS
//     (write pattern re-verified conflict-free), raw lgkm-only barriers.
// ---------------------------------------------------------------------------

typedef float  floatx4 __attribute__((ext_vector_type(4)));
typedef __bf16 bf16x8  __attribute__((ext_vector_type(8)));
typedef short  short8  __attribute__((ext_vector_type(8)));

union bfu { bf16x8 v; short8 s; };

#define LOG2E_X2 2.8853900817779268f
#define SB() __builtin_amdgcn_sched_barrier(0)

// raw barrier: wait own LDS ops only; global prefetches ride across.
#define BARX()                                             \
  do {                                                     \
    asm volatile("s_waitcnt lgkmcnt(0)" ::: "memory");     \
    SB();                                                  \
    __builtin_amdgcn_s_barrier();                          \
    SB();                                                  \
  } while (0)

// ---- kernel 0: W[512:1536,:] -> fragment-packed bf16 B.
// Bp frag(T,wc,ct) base elem = ((T*4+wc)*8+ct)*512; lane (q*16+t) holds 8 k.
__global__ void wt_convert(const float* __restrict__ W, __bf16* __restrict__ Bp) {
  __shared__ float tile[64][65];                 // +1 pad: conflict-free both ways
  const int kt = blockIdx.x >> 3;                // 16 k-tiles (64 k each)
  const int nt = blockIdx.x & 7;                 // 8 n-tiles (64 n each)
  const int c  = threadIdx.x & 63;
  const int r4 = threadIdx.x >> 6;               // 4 rows per pass
  #pragma unroll 4
  for (int i = 0; i < 16; i++) {
    int r = i * 4 + r4;                          // k-local
    tile[r][c] = W[(long)(512 + kt * 64 + r) * 512 + nt * 64 + c];
  }
  __syncthreads();
  const int n_loc = threadIdx.x & 63;
  const int kc4   = threadIdx.x >> 6;            // 0..3
  const int n_g   = nt * 64 + n_loc;
  const int wc    = n_g >> 7;
  const int ct    = (n_g >> 4) & 7;
  const int t     = n_g & 15;
  #pragma unroll
  for (int i = 0; i < 2; i++) {
    int chunk = i * 4 + kc4;                     // k_loc = chunk*8 + j
    int k_g   = kt * 64 + chunk * 8;
    int T     = k_g >> 5;
    int q     = (k_g >> 3) & 3;
    union bfu u;
    #pragma unroll
    for (int j = 0; j < 8; j++) u.v[j] = (__bf16)tile[chunk * 8 + j][n_loc];
    long cidx = ((long)(T * 4 + wc) * 8 + ct) * 64 + q * 16 + t;
    *(bf16x8*)(Bp + cidx * 8) = u.v;
  }
}

// ---- kernel 1: hproj[b][n] = bias[n] + sum_k hidden[b,k] * W[k,n]  (k<512)
__global__ void hproj_kernel(const float* __restrict__ hidden,
                             const float* __restrict__ W,
                             const float* __restrict__ bias,
                             float* __restrict__ hproj) {
  const int tid = threadIdx.x;            // n
  const int b_  = blockIdx.x >> 2;
  const int kc  = blockIdx.x & 3;
  __shared__ float hid[128];
  if (tid < 128) hid[tid] = hidden[b_ * 512 + kc * 128 + tid];
  __syncthreads();
  float acc = (kc == 0) ? bias[tid] : 0.f;
  const float* Wp = W + (long)(kc * 128) * 512 + tid;
  #pragma unroll 8
  for (int k = 0; k < 128; k++) acc = fmaf(hid[k], Wp[(long)k * 512], acc);
  atomicAdd(&hproj[b_ * 512 + tid], acc);
}

// ---- kernel 2: GEMM + tanh/v-dot epilogue; BK=128 mega-phases.
// LDS buffer (bf16, 16KB): k-local kk=s*32+c*8+j (s=step 0..3):
//   elem addr = s*2048 + c*512 + ((m*8) ^ (c*16)) + j
// Staging: thread (m = tid&63, h = tid>>6) loads 32 contiguous floats of
// row m at cols [P*128 + h*32, +32): per-row 512B contiguous per phase.
// Writes: chunk i2 (c=i2, s=h): 16 lanes (m=0..15) span 256B -> conflict-free.
// Reads (step s): same verified R5 pattern at +s*2048.
__global__ __launch_bounds__(256, 2) void gemm_score(
    const float* __restrict__ enc,    // [65536][1024] fp32
    const __bf16* __restrict__ Bp,    // packed B, 1 MB
    const float* __restrict__ hproj,  // [64][512]
    const float* __restrict__ v,      // [512]
    float* __restrict__ scores)       // [64][1024]  ([b][s])
{
  __shared__ __bf16 ldsA[2][8192];   // 2 x 16 KB
  __shared__ float bscore[64];

  const int tid  = threadIdx.x;
  const int lane = tid & 63;
  const int wc   = tid >> 6;      // wave -> n-range [wc*128, +128); also h
  const int q    = lane >> 4;
  const int t    = lane & 15;
  const long m0  = (long)blockIdx.x * 64;

  const int sm  = tid & 63;       // staging row
  const int h   = tid >> 6;       // staging k-slice (== step index s it fills)
  const int sm8 = sm * 8;
  const float* ap = enc + (m0 + sm) * 1024 + h * 32;

  // fragment read bases (step/rt offsets are compile-time immediates)
  const __bf16* ar0 = &ldsA[0][q * 512 + ((t * 8) ^ (q * 16))];
  const __bf16* ar1 = &ldsA[1][q * 512 + ((t * 8) ^ (q * 16))];

  // packed-B per-lane base
  const __bf16* bpb = Bp + (long)wc * 4096 + (long)lane * 8;

  if (tid < 64) bscore[tid] = 0.f;

  floatx4 acc[4][8];
  #pragma unroll
  for (int i = 0; i < 4; i++)
    #pragma unroll
    for (int j = 0; j < 8; j++)
      acc[i][j] = (floatx4){0.f, 0.f, 0.f, 0.f};

  floatx4 ra[8];       // A staging: 32 floats = 8 x float4 (32 VGPR)
  short8  bfr[2][8];   // B fragments, rolling double buffer (64 VGPR)

  auto issueA = [&](int P) {                 // 8 coalesced 16B loads (HBM)
    const float* p = ap + P * 128;
    #pragma unroll
    for (int i = 0; i < 8; i++) ra[i] = *(const floatx4*)(p + i * 4);
  };
  auto writeA = [&](int b) {                 // cvt once + 4 x 16B ds_write
    __bf16* dst = &ldsA[b][h * 2048];
    #pragma unroll
    for (int i2 = 0; i2 < 4; i2++) {
      union bfu u;
      #pragma unroll
      for (int j = 0; j < 4; j++) {
        u.v[j]     = (__bf16)ra[2 * i2][j];
        u.v[4 + j] = (__bf16)ra[2 * i2 + 1][j];
      }
      *(bf16x8*)(dst + i2 * 512 + (sm8 ^ (i2 * 16))) = u.v;
    }
  };
  auto loadB = [&](int T, int bs) {          // 8 coalesced 1KB wave-loads (L2)
    #pragma unroll
    for (int ct = 0; ct < 8; ct++) {
      union bfu u;
      u.v = *(const bf16x8*)(bpb + (long)T * 16384 + ct * 512);
      bfr[bs][ct] = u.s;
    }
  };
  auto compute = [&](int b, int s, int bs) { // one K-step: 4 ds_read + 32 MFMA
    const __bf16* base = (b ? ar1 : ar0) + s * 2048;
    #pragma unroll
    for (int rt = 0; rt < 4; rt++) {
      union bfu u;
      u.v = *(const bf16x8*)(base + rt * 128);
      #pragma unroll
      for (int ct = 0; ct < 8; ct++)
        acc[rt][ct] = __builtin_amdgcn_mfma_f32_16x16x32_bf16(
            u.s, bfr[bs][ct], acc[rt][ct], 0, 0, 0);
    }
  };

  // prologue: A(P=0) staged into buf0; B(0),B(1) in regs.
  issueA(0);
  loadB(0, 0); loadB(1, 1);
  writeA(0);                   // counted vmcnt wait for ra only; B stays in flight
  BARX();

  // Mega-phase P (reads buf[P&1], writes buf[(P&1)^1]):
  //   issueA(P+1) first (8 HBM loads fly under ~4 steps of compute);
  //   4 K-steps x 32 MFMA with B rolling 1 ahead (first B-wait that forces
  //   A(P) retirement is 2 steps after A(P) was issued last phase);
  //   cvt+write A(P+1) (A issued at phase start -> covered); 1 barrier.
#define PHASE(P)                                           \
  {                                                        \
    if ((P) < 7) issueA((P) + 1);                          \
    compute((P) & 1, 0, 0);                                \
    loadB((P) * 4 + 2, 0);                                 \
    compute((P) & 1, 1, 1);                                \
    loadB((P) * 4 + 3, 1);                                 \
    compute((P) & 1, 2, 0);                                \
    if ((P) < 7) loadB((P) * 4 + 4, 0);                    \
    compute((P) & 1, 3, 1);                                \
    if ((P) < 7) loadB((P) * 4 + 5, 1);                    \
    if ((P) < 7) { writeA(((P) & 1) ^ 1); BARX(); }        \
  }

  PHASE(0) PHASE(1) PHASE(2) PHASE(3)
  PHASE(4) PHASE(5) PHASE(6) PHASE(7)
#undef PHASE

  // ---- epilogue: score[row] = sum_n v[n] * tanh(acc + hproj[row][n])
  // rows 0..63: global m = blk*64+row = s*64+b -> s=blk, b=row.
  float vv[8];
  #pragma unroll
  for (int ct = 0; ct < 8; ct++) vv[ct] = v[wc * 128 + ct * 16 + t];

  #pragma unroll
  for (int rt = 0; rt < 4; rt++) {
    #pragma unroll
    for (int r = 0; r < 4; r++) {
      int row = rt * 16 + q * 4 + r;              // C/D: row=(lane>>4)*4+reg
      const float* hrow = hproj + row * 512 + wc * 128 + t;
      float s = 0.f;
      #pragma unroll
      for (int ct = 0; ct < 8; ct++) {
        float e  = acc[rt][ct][r] + hrow[ct * 16];
        float ex = __builtin_amdgcn_exp2f(e * LOG2E_X2);        // e^(2x)
        float th = 1.f - 2.f * __builtin_amdgcn_rcpf(ex + 1.f); // tanh(x)
        s = fmaf(vv[ct], th, s);
      }
      s += __shfl_xor(s, 1);
      s += __shfl_xor(s, 2);
      s += __shfl_xor(s, 4);
      s += __shfl_xor(s, 8);
      if (t == 0) atomicAdd(&bscore[row], s);
    }
  }
  __syncthreads();   // once, end of kernel
  if (tid < 64) scores[(long)tid * 1024 + blockIdx.x] = bscore[tid];
}

// ---- kernel 3: softmax over s for each b
__global__ void softmax_kernel(const float* __restrict__ scores,
                               float* __restrict__ out) {
  const int b_   = blockIdx.x;
  const int tid  = threadIdx.x;
  const int lane = tid & 63;
  const int wv   = tid >> 6;
  __shared__ float redmax[4], redsum[4];

  float x[4];
  #pragma unroll
  for (int i = 0; i < 4; i++) x[i] = scores[b_ * 1024 + i * 256 + tid];
  float mx = fmaxf(fmaxf(x[0], x[1]), fmaxf(x[2], x[3]));
  #pragma unroll
  for (int off = 1; off < 64; off <<= 1) mx = fmaxf(mx, __shfl_xor(mx, off));
  if (lane == 0) redmax[wv] = mx;
  __syncthreads();
  mx = fmaxf(fmaxf(redmax[0], redmax[1]), fmaxf(redmax[2], redmax[3]));

  float e[4], s = 0.f;
  #pragma unroll
  for (int i = 0; i < 4; i++) { e[i] = __expf(x[i] - mx); s += e[i]; }
  #pragma unroll
  for (int off = 1; off < 64; off <<= 1) s += __shfl_xor(s, off);
  if (lane == 0) redsum[wv] = s;
  __syncthreads();
  s = redsum[0] + redsum[1] + redsum[2] + redsum[3];
  float inv = 1.f / s;
  #pragma unroll
  for (int i = 0; i < 4; i++) out[b_ * 1024 + i * 256 + tid] = e[i] * inv;
}

extern "C" void kernel_launch(void* const* d_in, const int* in_sizes, int n_in,
                              void* d_out, int out_size, void* d_ws, size_t ws_size,
                              hipStream_t stream) {
  (void)in_sizes; (void)n_in; (void)out_size; (void)ws_size;
  const float* hidden = (const float*)d_in[0];   // [64,512]
  const float* enc    = (const float*)d_in[1];   // [1024,64,1024]
  const float* W      = (const float*)d_in[2];   // [1536,512]
  const float* bias   = (const float*)d_in[3];   // [512]
  const float* v      = (const float*)d_in[4];   // [512]
  float* out = (float*)d_out;                    // [64,1024]

  char* ws = (char*)d_ws;
  __bf16* Bp    = (__bf16*)ws;                            // 1 MB (packed B)
  float*  hproj = (float*)(ws + (1 << 20));               // 128 KB
  float*  scores= (float*)(ws + (1 << 20) + (128 << 10)); // 256 KB

  hipMemsetAsync(hproj, 0, 64 * 512 * sizeof(float), stream);
  wt_convert<<<128, 256, 0, stream>>>(W, Bp);
  hproj_kernel<<<256, 512, 0, stream>>>(hidden, W, bias, hproj);
  gemm_score<<<1024, 256, 0, stream>>>(enc, Bp, hproj, v, scores);
  softmax_kernel<<<64, 256, 0, stream>>>(scores, out);
}